// Round 18
// baseline (57.695 us; speedup 1.0000x reference)
//
#include <hip/hip_runtime.h>
#include <math.h>

#define BATCH 512
#define DIN   5120
#define DST   16
#define RK    160
#define NJ    192     // 160 dt_rank + 16 B + 16 C

typedef __attribute__((ext_vector_type(8))) __bf16 bf16x8;
typedef __attribute__((ext_vector_type(4))) float f32x4;
typedef __attribute__((ext_vector_type(8))) unsigned short ushort8;

// ws byte offsets (all 16B aligned)
#define OFF_XP    0u          // xP   [640 k8][512 b][8]  bf16
#define OFF_WP    5242880u    // WP   [640 k8][192 j][8]  bf16
#define OFF_WDTP  7208960u    // WdtP [20 k8][5120 d][8]  bf16
#define OFF_DTRP  8847360u    // dtrP [20 k8][512 b][8]   bf16
#define OFF_B     9011200u    // Bc   [512][16] f32
#define OFF_C     9043968u    // Cc   [512][16] f32

__device__ __forceinline__ unsigned short f2bf(float f) {
  unsigned int u = __float_as_uint(f);
  u = (u + 0x7FFFu + ((u >> 16) & 1u)) >> 16;   // RNE
  return (unsigned short)u;
}

// ---------------------------------------------------------------------------
// k_prep3: bf16 pack via LDS tile-transpose, 960 blocks (R15, unchanged).
// ---------------------------------------------------------------------------
__global__ __launch_bounds__(256) void k_prep3(
    const float* __restrict__ x, const float* __restrict__ Wdtr,
    const float* __restrict__ WB, const float* __restrict__ WC,
    const float* __restrict__ Wdt, char* __restrict__ ws)
{
  __shared__ unsigned short sT[64 * 168];
  const int t = threadIdx.x;
  const int bid = blockIdx.x;

  if (bid < 640) {            // ---- job A: xP ----
    const int bt = bid & 7, kt = bid >> 3;
    const int b0 = bt * 64, k0 = kt * 64;
#pragma unroll
    for (int i = 0; i < 4; ++i) {
      const int f = i * 256 + t;
      const int r = f >> 4, c = f & 15;
      const float4 v = *(const float4*)&x[(size_t)(b0 + r) * DIN + k0 + c * 4];
      unsigned short* p = &sT[r * 72 + c * 4];
      p[0] = f2bf(v.x); p[1] = f2bf(v.y); p[2] = f2bf(v.z); p[3] = f2bf(v.w);
    }
    __syncthreads();
    ushort8* xP = (ushort8*)(ws + OFF_XP);
#pragma unroll
    for (int i = 0; i < 2; ++i) {
      const int o = i * 256 + t;
      const int k8l = o >> 6, bl = o & 63;
      const unsigned short* p = &sT[bl * 72 + k8l * 8];
      ushort8 v;
#pragma unroll
      for (int e = 0; e < 8; ++e) v[e] = p[e];
      xP[(size_t)(kt * 8 + k8l) * 512 + b0 + bl] = v;
    }
  } else if (bid < 880) {     // ---- job B: WP ----
    const int bb = bid - 640;
    const int jt = bb % 3, kt = bb / 3;
    const int j0 = jt * 64, k0 = kt * 64;
#pragma unroll
    for (int i = 0; i < 4; ++i) {
      const int f = i * 256 + t;
      const int r = f >> 4, c = f & 15;
      const int j = j0 + r;
      const float* row;
      if (j < RK)            row = Wdtr + (size_t)j * DIN;
      else if (j < RK + DST) row = WB   + (size_t)(j - RK) * DIN;
      else                   row = WC   + (size_t)(j - RK - DST) * DIN;
      const float4 v = *(const float4*)&row[k0 + c * 4];
      unsigned short* p = &sT[r * 72 + c * 4];
      p[0] = f2bf(v.x); p[1] = f2bf(v.y); p[2] = f2bf(v.z); p[3] = f2bf(v.w);
    }
    __syncthreads();
    ushort8* WPo = (ushort8*)(ws + OFF_WP);
#pragma unroll
    for (int i = 0; i < 2; ++i) {
      const int o = i * 256 + t;
      const int k8l = o >> 6, jl = o & 63;
      const unsigned short* p = &sT[jl * 72 + k8l * 8];
      ushort8 v;
#pragma unroll
      for (int e = 0; e < 8; ++e) v[e] = p[e];
      WPo[(size_t)(kt * 8 + k8l) * 192 + j0 + jl] = v;
    }
  } else {                    // ---- job C: WdtP ----
    const int d0 = (bid - 880) * 64;
#pragma unroll
    for (int i = 0; i < 10; ++i) {
      const int f = i * 256 + t;
      const int r = f / 40, c = f - r * 40;
      const float4 v = *(const float4*)&Wdt[(size_t)(d0 + r) * RK + c * 4];
      unsigned short* p = &sT[r * 168 + c * 4];
      p[0] = f2bf(v.x); p[1] = f2bf(v.y); p[2] = f2bf(v.z); p[3] = f2bf(v.w);
    }
    __syncthreads();
    ushort8* WdtPo = (ushort8*)(ws + OFF_WDTP);
#pragma unroll
    for (int i = 0; i < 5; ++i) {
      const int o = i * 256 + t;
      const int k8l = o >> 6, dl = o & 63;
      const unsigned short* p = &sT[dl * 168 + k8l * 8];
      ushort8 v;
#pragma unroll
      for (int e = 0; e < 8; ++e) v[e] = p[e];
      WdtPo[(size_t)k8l * 5120 + d0 + dl] = v;
    }
  }
}

// ---------------------------------------------------------------------------
// k_g1f2: GEMM1 with in-block split-K (R15, unchanged). 384 x 1024.
// ---------------------------------------------------------------------------
__global__ __launch_bounds__(1024) void k_g1f2(char* __restrict__ ws)
{
  __shared__ float4 red[16][64];

  const int t = threadIdx.x;
  const int w = t >> 6, l = t & 63;
  const int jt = blockIdx.x >> 5, bt = blockIdx.x & 31;
  const int j0 = jt * 16, b0 = bt * 16;

  const bf16x8* WPv = (const bf16x8*)(ws + OFF_WP);
  const bf16x8* xPv = (const bf16x8*)(ws + OFF_XP);

  const int lg = l >> 4, lr = l & 15;
  f32x4 acc = {0.f, 0.f, 0.f, 0.f};

#pragma unroll
  for (int s = 0; s < 10; ++s) {
    const int k8 = w * 40 + s * 4 + lg;
    const bf16x8 av = WPv[(size_t)k8 * 192 + j0 + lr];
    const bf16x8 bv = xPv[(size_t)k8 * 512 + b0 + lr];
    acc = __builtin_amdgcn_mfma_f32_16x16x32_bf16(av, bv, acc, 0, 0, 0);
  }

  red[w][l] = (float4){acc[0], acc[1], acc[2], acc[3]};
  __syncthreads();

  if (t < 256) {
    const int ll = t >> 2, r = t & 3;
    const float* rp = (const float*)red;
    float s = 0.f;
#pragma unroll
    for (int ww = 0; ww < 16; ++ww)
      s += rp[(ww * 64 + ll) * 4 + r];

    const int j = j0 + (ll >> 4) * 4 + r;
    const int b = b0 + (ll & 15);
    if (jt < 10) {
      unsigned short* dtrP = (unsigned short*)(ws + OFF_DTRP);
      dtrP[((size_t)(j >> 3) * 512 + b) * 8 + (j & 7)] = f2bf(s);
    } else if (jt == 10) {
      ((float*)(ws + OFF_B))[(size_t)b * DST + (j - 160)] = s;
    } else {
      ((float*)(ws + OFF_C))[(size_t)b * DST + (j - 176)] = s;
    }
  }
}

// ---------------------------------------------------------------------------
// k_g2y4: R17 structure + NON-TEMPORAL h loads and y stores. h is stream-once
// (168 MB) — nt bypasses L2/L3 allocation so the cached paths (x, dt
// operands, B/C, A) stay resident; y writes skip write-allocate.
// ---------------------------------------------------------------------------
__global__ __launch_bounds__(256) void k_g2y4(
    const float* __restrict__ bdt, const float* __restrict__ A,
    const float* __restrict__ Dp,  const float* __restrict__ x,
    const float* __restrict__ h,   float* __restrict__ y,
    char* __restrict__ ws)
{
  __shared__ float sDT[4][16][33];
  __shared__ float sB[4][16][16];
  __shared__ float sC[4][16][16];
  __shared__ float sX[4][16][32];

  const int w = threadIdx.x >> 6;
  const int l = threadIdx.x & 63;
  const int wid = blockIdx.x * 4 + w;           // 0..5119
  const int dtile = wid % 160, btile = wid / 160;
  const int d0 = dtile * 32, b0 = btile * 16;

  const int q = l & 3;
  const int Q = l >> 2;
  const int dA_ = d0 + Q, dB_ = d0 + 16 + Q;

  // ---- h prefetch (non-temporal) + A/Dp loads issued first ----
  const f32x4* hpA = (const f32x4*)(h + ((size_t)b0 * DIN + dA_) * DST + q * 4);
  const f32x4* hpB = (const f32x4*)(h + ((size_t)b0 * DIN + dB_) * DST + q * 4);
  const size_t jstep = (size_t)DIN * DST / 4;   // in f32x4 units

  f32x4 hA0 = __builtin_nontemporal_load(hpA);
  f32x4 hB0 = __builtin_nontemporal_load(hpB);
  f32x4 hA1 = __builtin_nontemporal_load(hpA + jstep);
  f32x4 hB1 = __builtin_nontemporal_load(hpB + jstep);
  const float4 Aa = *(const float4*)(A + (size_t)dA_ * DST + q * 4);
  const float4 Ab = *(const float4*)(A + (size_t)dB_ * DST + q * 4);
  const float  DvA = Dp[dA_], DvB = Dp[dB_];

  const bf16x8* dtrPv = (const bf16x8*)(ws + OFF_DTRP);
  const bf16x8* WdtPv = (const bf16x8*)(ws + OFF_WDTP);
  const float*  Bc    = (const float*)(ws + OFF_B);
  const float*  Cc    = (const float*)(ws + OFF_C);

  // ---- stage Bc/Cc and x tile (wave-private LDS) ----
  *(float4*)&((float*)sB[w])[l * 4] = *(const float4*)&Bc[b0 * DST + l * 4];
  *(float4*)&((float*)sC[w])[l * 4] = *(const float4*)&Cc[b0 * DST + l * 4];
#pragma unroll
  for (int i = 0; i < 2; ++i) {
    const int o = i * 64 + l;
    const int xr = o >> 3, xc = (o & 7) * 4;
    *(float4*)&sX[w][xr][xc] = *(const float4*)&x[(size_t)(b0 + xr) * DIN + d0 + xc];
  }

  // ---- dt tiles via MFMA (A-fragment shared across both d-halves) ----
  const int lg = l >> 4, lr = l & 15;
  f32x4 acc0 = {0.f, 0.f, 0.f, 0.f}, acc1 = acc0;
#pragma unroll
  for (int s = 0; s < 5; ++s) {
    const int k8 = s * 4 + lg;
    const bf16x8 av  = dtrPv[(size_t)k8 * 512 + b0 + lr];
    const bf16x8 bv0 = WdtPv[(size_t)k8 * 5120 + d0 + lr];
    const bf16x8 bv1 = WdtPv[(size_t)k8 * 5120 + d0 + 16 + lr];
    acc0 = __builtin_amdgcn_mfma_f32_16x16x32_bf16(av, bv0, acc0, 0, 0, 0);
    acc1 = __builtin_amdgcn_mfma_f32_16x16x32_bf16(av, bv1, acc1, 0, 0, 0);
  }
  const float bias0 = bdt[d0 + lr];
  const float bias1 = bdt[d0 + 16 + lr];
#pragma unroll
  for (int r = 0; r < 4; ++r) {
    const float p0 = acc0[r] + bias0;
    const float p1 = acc1[r] + bias1;
    sDT[w][lg * 4 + r][lr]      = (p0 > 20.f) ? p0 : log1pf(__expf(p0));
    sDT[w][lg * 4 + r][16 + lr] = (p1 > 20.f) ? p1 : log1pf(__expf(p1));
  }
  // no barrier: all LDS buffers wave-private (R17-verified)

  float* ypA = y + (size_t)b0 * DIN + dA_;
  float* ypB = y + (size_t)b0 * DIN + dB_;

#pragma unroll
  for (int j = 0; j < 16; ++j) {
    const f32x4 h4a = (j & 1) ? hA1 : hA0;
    const f32x4 h4b = (j & 1) ? hB1 : hB0;
    if (j + 2 < 16) {
      if (j & 1) { hA1 = __builtin_nontemporal_load(hpA + (size_t)(j + 2) * jstep);
                   hB1 = __builtin_nontemporal_load(hpB + (size_t)(j + 2) * jstep); }
      else       { hA0 = __builtin_nontemporal_load(hpA + (size_t)(j + 2) * jstep);
                   hB0 = __builtin_nontemporal_load(hpB + (size_t)(j + 2) * jstep); }
    }

    const float4 B4 = *(const float4*)&sB[w][j][q * 4];
    const float4 C4 = *(const float4*)&sC[w][j][q * 4];

    const float dtvA = sDT[w][j][Q];
    const float dtvB = sDT[w][j][16 + Q];
    const float xvA  = sX[w][j][Q];
    const float xvB  = sX[w][j][16 + Q];
    const float dtxA = dtvA * xvA;
    const float dtxB = dtvB * xvB;

    float pA, pB;
    {
      const float e0 = __expf(Aa.x * dtvA), e1 = __expf(Aa.y * dtvA);
      const float e2 = __expf(Aa.z * dtvA), e3 = __expf(Aa.w * dtvA);
      const float n0 = fmaf(e0, h4a[0], dtxA * B4.x);
      const float n1 = fmaf(e1, h4a[1], dtxA * B4.y);
      const float n2 = fmaf(e2, h4a[2], dtxA * B4.z);
      const float n3 = fmaf(e3, h4a[3], dtxA * B4.w);
      pA = n0 * C4.x + n1 * C4.y + n2 * C4.z + n3 * C4.w;
    }
    {
      const float e0 = __expf(Ab.x * dtvB), e1 = __expf(Ab.y * dtvB);
      const float e2 = __expf(Ab.z * dtvB), e3 = __expf(Ab.w * dtvB);
      const float n0 = fmaf(e0, h4b[0], dtxB * B4.x);
      const float n1 = fmaf(e1, h4b[1], dtxB * B4.y);
      const float n2 = fmaf(e2, h4b[2], dtxB * B4.z);
      const float n3 = fmaf(e3, h4b[3], dtxB * B4.w);
      pB = n0 * C4.x + n1 * C4.y + n2 * C4.z + n3 * C4.w;
    }

    pA += __shfl_xor(pA, 1);
    pA += __shfl_xor(pA, 2);
    pB += __shfl_xor(pB, 1);
    pB += __shfl_xor(pB, 2);
    if (q == 0) {
      __builtin_nontemporal_store(fmaf(DvA, xvA, pA), ypA + (size_t)j * DIN);
      __builtin_nontemporal_store(fmaf(DvB, xvB, pB), ypB + (size_t)j * DIN);
    }
  }
}

extern "C" void kernel_launch(void* const* d_in, const int* in_sizes, int n_in,
                              void* d_out, int out_size, void* d_ws, size_t ws_size,
                              hipStream_t stream) {
  const float* x    = (const float*)d_in[0];
  const float* Wdtr = (const float*)d_in[1];
  const float* Wdt  = (const float*)d_in[2];
  const float* bdt  = (const float*)d_in[3];
  const float* WB   = (const float*)d_in[4];
  const float* WC   = (const float*)d_in[5];
  const float* A    = (const float*)d_in[6];
  const float* Dp   = (const float*)d_in[7];
  const float* h    = (const float*)d_in[8];
  float* y = (float*)d_out;
  char* ws = (char*)d_ws;

  k_prep3<<<dim3(960), 256, 0, stream>>>(x, Wdtr, WB, WC, Wdt, ws);
  k_g1f2<<<dim3(384), 1024, 0, stream>>>(ws);
  k_g2y4<<<dim3(1280), 256, 0, stream>>>(bdt, A, Dp, x, h, y, ws);
}

// Round 19
// 50.420 us; speedup vs baseline: 1.1443x; 1.1443x over previous
//
#include <hip/hip_runtime.h>
#include <math.h>

#define BATCH 512
#define DIN   5120
#define DST   16
#define RK    160
#define NJ    192     // 160 dt_rank + 16 B + 16 C

typedef __attribute__((ext_vector_type(8))) __bf16 bf16x8;
typedef __attribute__((ext_vector_type(4))) float f32x4;
typedef __attribute__((ext_vector_type(8))) unsigned short ushort8;

// ws byte offsets (all 16B aligned)
#define OFF_XP    0u          // xP   [640 k8][512 b][8]  bf16
#define OFF_WP    5242880u    // WP   [640 k8][192 j][8]  bf16
#define OFF_WDTP  7208960u    // WdtP [20 k8][5120 d][8]  bf16
#define OFF_DTRP  8847360u    // dtrP [20 k8][512 b][8]   bf16
#define OFF_B     9011200u    // Bc   [512][16] f32
#define OFF_C     9043968u    // Cc   [512][16] f32

__device__ __forceinline__ unsigned short f2bf(float f) {
  unsigned int u = __float_as_uint(f);
  u = (u + 0x7FFFu + ((u >> 16) & 1u)) >> 16;   // RNE
  return (unsigned short)u;
}

// ---------------------------------------------------------------------------
// k_prep3: bf16 pack via LDS tile-transpose, 960 blocks (R15, unchanged).
// ---------------------------------------------------------------------------
__global__ __launch_bounds__(256) void k_prep3(
    const float* __restrict__ x, const float* __restrict__ Wdtr,
    const float* __restrict__ WB, const float* __restrict__ WC,
    const float* __restrict__ Wdt, char* __restrict__ ws)
{
  __shared__ unsigned short sT[64 * 168];
  const int t = threadIdx.x;
  const int bid = blockIdx.x;

  if (bid < 640) {            // ---- job A: xP ----
    const int bt = bid & 7, kt = bid >> 3;
    const int b0 = bt * 64, k0 = kt * 64;
#pragma unroll
    for (int i = 0; i < 4; ++i) {
      const int f = i * 256 + t;
      const int r = f >> 4, c = f & 15;
      const float4 v = *(const float4*)&x[(size_t)(b0 + r) * DIN + k0 + c * 4];
      unsigned short* p = &sT[r * 72 + c * 4];
      p[0] = f2bf(v.x); p[1] = f2bf(v.y); p[2] = f2bf(v.z); p[3] = f2bf(v.w);
    }
    __syncthreads();
    ushort8* xP = (ushort8*)(ws + OFF_XP);
#pragma unroll
    for (int i = 0; i < 2; ++i) {
      const int o = i * 256 + t;
      const int k8l = o >> 6, bl = o & 63;
      const unsigned short* p = &sT[bl * 72 + k8l * 8];
      ushort8 v;
#pragma unroll
      for (int e = 0; e < 8; ++e) v[e] = p[e];
      xP[(size_t)(kt * 8 + k8l) * 512 + b0 + bl] = v;
    }
  } else if (bid < 880) {     // ---- job B: WP ----
    const int bb = bid - 640;
    const int jt = bb % 3, kt = bb / 3;
    const int j0 = jt * 64, k0 = kt * 64;
#pragma unroll
    for (int i = 0; i < 4; ++i) {
      const int f = i * 256 + t;
      const int r = f >> 4, c = f & 15;
      const int j = j0 + r;
      const float* row;
      if (j < RK)            row = Wdtr + (size_t)j * DIN;
      else if (j < RK + DST) row = WB   + (size_t)(j - RK) * DIN;
      else                   row = WC   + (size_t)(j - RK - DST) * DIN;
      const float4 v = *(const float4*)&row[k0 + c * 4];
      unsigned short* p = &sT[r * 72 + c * 4];
      p[0] = f2bf(v.x); p[1] = f2bf(v.y); p[2] = f2bf(v.z); p[3] = f2bf(v.w);
    }
    __syncthreads();
    ushort8* WPo = (ushort8*)(ws + OFF_WP);
#pragma unroll
    for (int i = 0; i < 2; ++i) {
      const int o = i * 256 + t;
      const int k8l = o >> 6, jl = o & 63;
      const unsigned short* p = &sT[jl * 72 + k8l * 8];
      ushort8 v;
#pragma unroll
      for (int e = 0; e < 8; ++e) v[e] = p[e];
      WPo[(size_t)(kt * 8 + k8l) * 192 + j0 + jl] = v;
    }
  } else {                    // ---- job C: WdtP ----
    const int d0 = (bid - 880) * 64;
#pragma unroll
    for (int i = 0; i < 10; ++i) {
      const int f = i * 256 + t;
      const int r = f / 40, c = f - r * 40;
      const float4 v = *(const float4*)&Wdt[(size_t)(d0 + r) * RK + c * 4];
      unsigned short* p = &sT[r * 168 + c * 4];
      p[0] = f2bf(v.x); p[1] = f2bf(v.y); p[2] = f2bf(v.z); p[3] = f2bf(v.w);
    }
    __syncthreads();
    ushort8* WdtPo = (ushort8*)(ws + OFF_WDTP);
#pragma unroll
    for (int i = 0; i < 5; ++i) {
      const int o = i * 256 + t;
      const int k8l = o >> 6, dl = o & 63;
      const unsigned short* p = &sT[dl * 168 + k8l * 8];
      ushort8 v;
#pragma unroll
      for (int e = 0; e < 8; ++e) v[e] = p[e];
      WdtPo[(size_t)k8l * 5120 + d0 + dl] = v;
    }
  }
}

// ---------------------------------------------------------------------------
// k_g1f2: GEMM1 with in-block split-K (R15, unchanged). 384 x 1024.
// ---------------------------------------------------------------------------
__global__ __launch_bounds__(1024) void k_g1f2(char* __restrict__ ws)
{
  __shared__ float4 red[16][64];

  const int t = threadIdx.x;
  const int w = t >> 6, l = t & 63;
  const int jt = blockIdx.x >> 5, bt = blockIdx.x & 31;
  const int j0 = jt * 16, b0 = bt * 16;

  const bf16x8* WPv = (const bf16x8*)(ws + OFF_WP);
  const bf16x8* xPv = (const bf16x8*)(ws + OFF_XP);

  const int lg = l >> 4, lr = l & 15;
  f32x4 acc = {0.f, 0.f, 0.f, 0.f};

#pragma unroll
  for (int s = 0; s < 10; ++s) {
    const int k8 = w * 40 + s * 4 + lg;
    const bf16x8 av = WPv[(size_t)k8 * 192 + j0 + lr];
    const bf16x8 bv = xPv[(size_t)k8 * 512 + b0 + lr];
    acc = __builtin_amdgcn_mfma_f32_16x16x32_bf16(av, bv, acc, 0, 0, 0);
  }

  red[w][l] = (float4){acc[0], acc[1], acc[2], acc[3]};
  __syncthreads();

  if (t < 256) {
    const int ll = t >> 2, r = t & 3;
    const float* rp = (const float*)red;
    float s = 0.f;
#pragma unroll
    for (int ww = 0; ww < 16; ++ww)
      s += rp[(ww * 64 + ll) * 4 + r];

    const int j = j0 + (ll >> 4) * 4 + r;
    const int b = b0 + (ll & 15);
    if (jt < 10) {
      unsigned short* dtrP = (unsigned short*)(ws + OFF_DTRP);
      dtrP[((size_t)(j >> 3) * 512 + b) * 8 + (j & 7)] = f2bf(s);
    } else if (jt == 10) {
      ((float*)(ws + OFF_B))[(size_t)b * DST + (j - 160)] = s;
    } else {
      ((float*)(ws + OFF_C))[(size_t)b * DST + (j - 176)] = s;
    }
  }
}

// ---------------------------------------------------------------------------
// k_g2y2: fused dt-GEMM + softplus + h-stream, one wave per 16b x 32d task.
// 5120 tasks = 1280 blocks x 4 waves = exactly 20 waves/CU: single batch.
// (R16 form — best measured variant, 50.2 us. Cached h loads: L3 serves a
//  large fraction of h across graph replays; nt bypass regressed +7.5 us.)
// ---------------------------------------------------------------------------
__global__ __launch_bounds__(256) void k_g2y2(
    const float* __restrict__ bdt, const float* __restrict__ A,
    const float* __restrict__ Dp,  const float* __restrict__ x,
    const float* __restrict__ h,   float* __restrict__ y,
    char* __restrict__ ws)
{
  __shared__ float sDT[4][16][33];
  __shared__ float sB[4][16][16];
  __shared__ float sC[4][16][16];
  __shared__ float sX[4][16][32];

  const int w = threadIdx.x >> 6;
  const int l = threadIdx.x & 63;
  const int wid = blockIdx.x * 4 + w;           // 0..5119
  const int dtile = wid % 160, btile = wid / 160;
  const int d0 = dtile * 32, b0 = btile * 16;

  const bf16x8* dtrPv = (const bf16x8*)(ws + OFF_DTRP);
  const bf16x8* WdtPv = (const bf16x8*)(ws + OFF_WDTP);
  const float*  Bc    = (const float*)(ws + OFF_B);
  const float*  Cc    = (const float*)(ws + OFF_C);

  // stage Bc/Cc (16x16 each) and x tile (16b x 32d)
  *(float4*)&((float*)sB[w])[l * 4] = *(const float4*)&Bc[b0 * DST + l * 4];
  *(float4*)&((float*)sC[w])[l * 4] = *(const float4*)&Cc[b0 * DST + l * 4];
#pragma unroll
  for (int i = 0; i < 2; ++i) {
    const int o = i * 64 + l;                   // 0..127
    const int xr = o >> 3, xc = (o & 7) * 4;
    *(float4*)&sX[w][xr][xc] = *(const float4*)&x[(size_t)(b0 + xr) * DIN + d0 + xc];
  }

  // dt tiles via MFMA (both d-halves share the dtrP A-fragment)
  const int lg = l >> 4, lr = l & 15;
  f32x4 acc0 = {0.f, 0.f, 0.f, 0.f}, acc1 = acc0;
#pragma unroll
  for (int s = 0; s < 5; ++s) {
    const int k8 = s * 4 + lg;
    const bf16x8 av  = dtrPv[(size_t)k8 * 512 + b0 + lr];
    const bf16x8 bv0 = WdtPv[(size_t)k8 * 5120 + d0 + lr];
    const bf16x8 bv1 = WdtPv[(size_t)k8 * 5120 + d0 + 16 + lr];
    acc0 = __builtin_amdgcn_mfma_f32_16x16x32_bf16(av, bv0, acc0, 0, 0, 0);
    acc1 = __builtin_amdgcn_mfma_f32_16x16x32_bf16(av, bv1, acc1, 0, 0, 0);
  }
  const float bias0 = bdt[d0 + lr];
  const float bias1 = bdt[d0 + 16 + lr];
#pragma unroll
  for (int r = 0; r < 4; ++r) {
    const float p0 = acc0[r] + bias0;
    const float p1 = acc1[r] + bias1;
    sDT[w][lg * 4 + r][lr]      = (p0 > 20.f) ? p0 : log1pf(__expf(p0));
    sDT[w][lg * 4 + r][16 + lr] = (p1 > 20.f) ? p1 : log1pf(__expf(p1));
  }
  __syncthreads();

  // h-stream: quad q owns states q*4..q*4+3; Q = d offset; two d's per lane.
  const int q = l & 3;
  const int Q = l >> 2;
  const int dA_ = d0 + Q, dB_ = d0 + 16 + Q;

  const float4 Aa = *(const float4*)(A + (size_t)dA_ * DST + q * 4);
  const float4 Ab = *(const float4*)(A + (size_t)dB_ * DST + q * 4);
  const float  DvA = Dp[dA_], DvB = Dp[dB_];

  const float* hpA = h + ((size_t)b0 * DIN + dA_) * DST + q * 4;
  const float* hpB = h + ((size_t)b0 * DIN + dB_) * DST + q * 4;
  float* ypA = y + (size_t)b0 * DIN + dA_;
  float* ypB = y + (size_t)b0 * DIN + dB_;
  const size_t jstep = (size_t)DIN * DST;

  // depth-2 rotating prefetch (static indices)
  float4 hA0 = *(const float4*)(hpA);
  float4 hB0 = *(const float4*)(hpB);
  float4 hA1 = *(const float4*)(hpA + jstep);
  float4 hB1 = *(const float4*)(hpB + jstep);

#pragma unroll
  for (int j = 0; j < 16; ++j) {
    const float4 h4a = (j & 1) ? hA1 : hA0;
    const float4 h4b = (j & 1) ? hB1 : hB0;
    if (j + 2 < 16) {
      if (j & 1) { hA1 = *(const float4*)(hpA + (size_t)(j + 2) * jstep);
                   hB1 = *(const float4*)(hpB + (size_t)(j + 2) * jstep); }
      else       { hA0 = *(const float4*)(hpA + (size_t)(j + 2) * jstep);
                   hB0 = *(const float4*)(hpB + (size_t)(j + 2) * jstep); }
    }

    const float4 B4 = *(const float4*)&sB[w][j][q * 4];
    const float4 C4 = *(const float4*)&sC[w][j][q * 4];

    const float dtvA = sDT[w][j][Q];
    const float dtvB = sDT[w][j][16 + Q];
    const float xvA  = sX[w][j][Q];
    const float xvB  = sX[w][j][16 + Q];
    const float dtxA = dtvA * xvA;
    const float dtxB = dtvB * xvB;

    float pA, pB;
    {
      const float e0 = __expf(Aa.x * dtvA), e1 = __expf(Aa.y * dtvA);
      const float e2 = __expf(Aa.z * dtvA), e3 = __expf(Aa.w * dtvA);
      const float n0 = fmaf(e0, h4a.x, dtxA * B4.x);
      const float n1 = fmaf(e1, h4a.y, dtxA * B4.y);
      const float n2 = fmaf(e2, h4a.z, dtxA * B4.z);
      const float n3 = fmaf(e3, h4a.w, dtxA * B4.w);
      pA = n0 * C4.x + n1 * C4.y + n2 * C4.z + n3 * C4.w;
    }
    {
      const float e0 = __expf(Ab.x * dtvB), e1 = __expf(Ab.y * dtvB);
      const float e2 = __expf(Ab.z * dtvB), e3 = __expf(Ab.w * dtvB);
      const float n0 = fmaf(e0, h4b.x, dtxB * B4.x);
      const float n1 = fmaf(e1, h4b.y, dtxB * B4.y);
      const float n2 = fmaf(e2, h4b.z, dtxB * B4.z);
      const float n3 = fmaf(e3, h4b.w, dtxB * B4.w);
      pB = n0 * C4.x + n1 * C4.y + n2 * C4.z + n3 * C4.w;
    }

    pA += __shfl_xor(pA, 1);
    pA += __shfl_xor(pA, 2);
    pB += __shfl_xor(pB, 1);
    pB += __shfl_xor(pB, 2);
    if (q == 0) {
      ypA[(size_t)j * DIN] = fmaf(DvA, xvA, pA);
      ypB[(size_t)j * DIN] = fmaf(DvB, xvB, pB);
    }
  }
}

extern "C" void kernel_launch(void* const* d_in, const int* in_sizes, int n_in,
                              void* d_out, int out_size, void* d_ws, size_t ws_size,
                              hipStream_t stream) {
  const float* x    = (const float*)d_in[0];
  const float* Wdtr = (const float*)d_in[1];
  const float* Wdt  = (const float*)d_in[2];
  const float* bdt  = (const float*)d_in[3];
  const float* WB   = (const float*)d_in[4];
  const float* WC   = (const float*)d_in[5];
  const float* A    = (const float*)d_in[6];
  const float* Dp   = (const float*)d_in[7];
  const float* h    = (const float*)d_in[8];
  float* y = (float*)d_out;
  char* ws = (char*)d_ws;

  k_prep3<<<dim3(960), 256, 0, stream>>>(x, Wdtr, WB, WC, Wdt, ws);
  k_g1f2<<<dim3(384), 1024, 0, stream>>>(ws);
  k_g2y2<<<dim3(1280), 256, 0, stream>>>(bdt, A, Dp, x, h, y, ws);
}